// Round 4
// baseline (262.704 us; speedup 1.0000x reference)
//
#include <hip/hip_runtime.h>

typedef unsigned short u16;
typedef unsigned int u32;
typedef __bf16 bf16x8 __attribute__((ext_vector_type(8)));
typedef u16 u16x8 __attribute__((ext_vector_type(8)));
typedef float floatx4 __attribute__((ext_vector_type(4)));

#define MFMA16(a, b, c) __builtin_amdgcn_mfma_f32_16x16x32_bf16((a), (b), (c), 0, 0, 0)

#define B_ 2
#define S0 4096
#define NH 16
#define HD 64
#define HID 1024

__device__ __forceinline__ float bf2f(u16 u) {
  union { u32 i; float f; } x; x.i = ((u32)u) << 16; return x.f;
}
__device__ __forceinline__ u16 f2bf(float f) {
  union { float f; u32 i; } x; x.f = f;
  u32 r = x.i + 0x7FFFu + ((x.i >> 16) & 1u);
  return (u16)(r >> 16);
}

// -------- X (fp32) -> bf16 --------------------------------------------------
__global__ __launch_bounds__(256) void convert_x(const float* __restrict__ X,
                                                 u16* __restrict__ dst) {
  int i = (blockIdx.x * 256 + threadIdx.x) * 8;
  u16x8 v;
#pragma unroll
  for (int j = 0; j < 8; j++) v[j] = f2bf(X[i + j]);
  *(u16x8*)(dst + i) = v;
}

// -------- mask + 4 biases (fp32) -> bf16 ------------------------------------
__global__ __launch_bounds__(256) void convert_small(
    const float* __restrict__ mask, const float* __restrict__ bq,
    const float* __restrict__ bk, const float* __restrict__ bv,
    const float* __restrict__ bo, u16* __restrict__ cmask,
    u16* __restrict__ cb) {
  int tid = blockIdx.x * 256 + threadIdx.x;
  if (tid < B_ * S0) {
    cmask[tid] = f2bf(mask[tid]);
  } else {
    int j = tid - B_ * S0;  // [0, 4096)
    int seg = j >> 10, idx = j & 1023;
    const float* src = (seg == 0) ? bq : (seg == 1) ? bk : (seg == 2) ? bv : bo;
    cb[seg * 1024 + idx] = f2bf(src[idx]);
  }
}

// -------- weight transpose: W[k][n] (fp32) -> Wt[n][k] (bf16), 4 matrices ---
__global__ __launch_bounds__(256) void transpose4(
    const float* __restrict__ Wq, const float* __restrict__ Wk,
    const float* __restrict__ Wv, const float* __restrict__ Wo,
    u16* __restrict__ WqkvT, u16* __restrict__ WoT) {
  __shared__ u16 tile[64][66];
  int mat = blockIdx.z;
  const float* src = (mat == 0) ? Wq : (mat == 1) ? Wk : (mat == 2) ? Wv : Wo;
  u16* dst = (mat < 3) ? (WqkvT + (size_t)mat * HID * HID) : WoT;
  int t0 = blockIdx.x * 64;  // k base
  int c0 = blockIdx.y * 64;  // n base
  int tx = threadIdx.x & 63, ty = threadIdx.x >> 6;
#pragma unroll
  for (int i = 0; i < 16; i++) {
    int r = i * 4 + ty;
    tile[r][tx] = f2bf(src[(size_t)(t0 + r) * HID + c0 + tx]);
  }
  __syncthreads();
#pragma unroll
  for (int i = 0; i < 16; i++) {
    int r = i * 4 + ty;
    dst[(size_t)(c0 + r) * HID + t0 + tx] = tile[tx][r];
  }
}

// ---------------- bf16 GEMM: C[m][n] = A[m][k] * Bt[n][k] + bias -----------
// mode 0: N=3072 fused QKV, scatter bf16 to qkv[p][b][h][s][d] + bias cb[0..2]
// mode 1: N=1024, write fp32 row-major out + bias cb[3]
__global__ __launch_bounds__(256) void gemm_bf16_tn(
    const u16* __restrict__ A, const u16* __restrict__ Bt,
    const u16* __restrict__ cb, void* __restrict__ outp, int K, int mode) {
  __shared__ alignas(16) u16 sA[128 * 32];
  __shared__ alignas(16) u16 sB[128 * 32];
  int t = threadIdx.x;
  int wave = t >> 6, lane = t & 63;
  int wm = wave >> 1, wn = wave & 1;
  int quad = lane >> 4, l16 = lane & 15;
  int tile_m = blockIdx.x * 128;
  int tile_n = blockIdx.y * 128;

  floatx4 acc[4][4] = {};

  int srow = wave * 16 + (lane >> 2);   // row within 64-row half-tile
  int scol = (lane & 3) * 8;            // k offset within 32-wide K-slab
  const u16* Ag = A + (size_t)(tile_m + srow) * K + scol;
  const u16* Bg = Bt + (size_t)(tile_n + srow) * K + scol;
  u16* sAp = sA + wave * 512 + lane * 8;  // == srow*32 + scol
  u16* sBp = sB + wave * 512 + lane * 8;
  size_t half = (size_t)64 * K;

  for (int k0 = 0; k0 < K; k0 += 32) {
    u16x8 va0 = *(const u16x8*)(Ag + k0);
    u16x8 va1 = *(const u16x8*)(Ag + half + k0);
    u16x8 vb0 = *(const u16x8*)(Bg + k0);
    u16x8 vb1 = *(const u16x8*)(Bg + half + k0);
    __syncthreads();  // all fragment reads of previous slab done
    *(u16x8*)(sAp) = va0;
    *(u16x8*)(sAp + 2048) = va1;
    *(u16x8*)(sBp) = vb0;
    *(u16x8*)(sBp + 2048) = vb1;
    __syncthreads();

    bf16x8 af[4], bfr[4];
#pragma unroll
    for (int mt = 0; mt < 4; mt++)
      af[mt] = *(const bf16x8*)(sA + (wm * 64 + mt * 16 + l16) * 32 + quad * 8);
#pragma unroll
    for (int nt = 0; nt < 4; nt++)
      bfr[nt] = *(const bf16x8*)(sB + (wn * 64 + nt * 16 + l16) * 32 + quad * 8);
#pragma unroll
    for (int mt = 0; mt < 4; mt++)
#pragma unroll
      for (int nt = 0; nt < 4; nt++)
        acc[mt][nt] = MFMA16(af[mt], bfr[nt], acc[mt][nt]);
  }

  if (mode == 0) {
    u16* op = (u16*)outp;
#pragma unroll
    for (int mt = 0; mt < 4; mt++) {
      int row0 = tile_m + wm * 64 + mt * 16 + quad * 4;
      int bb = row0 >> 12;
      int sbase = row0 & (S0 - 1);
#pragma unroll
      for (int nt = 0; nt < 4; nt++) {
        int col = tile_n + wn * 64 + nt * 16 + l16;
        int p = col >> 10;
        int rem = col & 1023;
        float bias = bf2f(cb[p * 1024 + rem]);
        int hh = rem >> 6, dd = rem & 63;
        u16* dp = op + ((size_t)(((p * 2 + bb) * NH + hh)) * S0 + sbase) * HD + dd;
#pragma unroll
        for (int r = 0; r < 4; r++)
          dp[(size_t)r * HD] = f2bf(acc[mt][nt][r] + bias);
      }
    }
  } else {
    float* op = (float*)outp;
#pragma unroll
    for (int mt = 0; mt < 4; mt++) {
      int row0 = tile_m + wm * 64 + mt * 16 + quad * 4;
#pragma unroll
      for (int nt = 0; nt < 4; nt++) {
        int col = tile_n + wn * 64 + nt * 16 + l16;
        float bias = bf2f(cb[3 * 1024 + col]);
        float* dp = op + (size_t)row0 * HID + col;
#pragma unroll
        for (int r = 0; r < 4; r++)
          dp[(size_t)r * HID] = acc[mt][nt][r] + bias;  // fp32 output
      }
    }
  }
}

// ---------------- windowed attention: one block per (b, h, chunk) ----------
__global__ __launch_bounds__(256) void attn_win(
    const u16* __restrict__ Q, const u16* __restrict__ Kp,
    const u16* __restrict__ Vp, const u16* __restrict__ cmask,
    u16* __restrict__ ctx) {
  __shared__ alignas(16) u16 sVt[64 * 200];      // [d][key], stride 200
  __shared__ alignas(16) u16 sP[4 * 16 * 200];   // [wave][qrow][key]
  __shared__ u16 sMk[192];

  int bid = blockIdx.x;
  int c = bid & 63;
  int h = (bid >> 6) & 15;
  int b = bid >> 10;
  int t = threadIdx.x;
  int wave = t >> 6, lane = t & 63;
  int quad = lane >> 4, l16 = lane & 15;

  const u16* Qb = Q + (size_t)(b * NH + h) * S0 * HD;
  const u16* Kb = Kp + (size_t)(b * NH + h) * S0 * HD;
  const u16* Vb = Vp + (size_t)(b * NH + h) * S0 * HD;
  int kbase = (c - 1) * 64;  // global key index of slot 0

  // stage V^T into LDS
#pragma unroll
  for (int i = 0; i < 48; i++) {
    int e = i * 256 + t;
    int slot = e >> 6, d = e & 63;
    int key = kbase + slot;
    int kc = key < 0 ? 0 : (key > S0 - 1 ? S0 - 1 : key);
    sVt[d * 200 + slot] = Vb[(size_t)kc * HD + d];
  }
  if (t < 192) {
    int j = kbase + t;
    sMk[t] = (j >= 0 && j < S0) ? cmask[(size_t)b * S0 + j] : (u16)0;
  }
  __syncthreads();

  // scores: D[q][key] = sum_d Q[q,d] K[key,d], fragments direct from global
  floatx4 sc[12] = {};
  int qrow = c * 64 + wave * 16 + l16;
#pragma unroll
  for (int ks = 0; ks < 2; ks++) {
    bf16x8 aq = *(const bf16x8*)(Qb + (size_t)qrow * HD + ks * 32 + quad * 8);
#pragma unroll
    for (int nt = 0; nt < 12; nt++) {
      int key = kbase + nt * 16 + l16;
      int kc = key < 0 ? 0 : (key > S0 - 1 ? S0 - 1 : key);
      bf16x8 bk = *(const bf16x8*)(Kb + (size_t)kc * HD + ks * 32 + quad * 8);
      sc[nt] = MFMA16(aq, bk, sc[nt]);
    }
  }

  // mask + softmax (rows live across the 16 lanes of a quad) + write P
  int qrel_base = wave * 16 + quad * 4;
  u16* myP = sP + wave * 16 * 200;
  float kmask[12];
#pragma unroll
  for (int nt = 0; nt < 12; nt++) kmask[nt] = bf2f(sMk[nt * 16 + l16]);

#pragma unroll
  for (int reg = 0; reg < 4; reg++) {
    int qrel = qrel_base + reg;
    float v[12];
    float m = -3e38f;
#pragma unroll
    for (int nt = 0; nt < 12; nt++) {
      int jr = nt * 16 + l16 - 64;  // key rel. chunk start
      bool ok = (jr >= qrel - 64) && (jr <= qrel + 64) && (kmask[nt] > 0.f);
      float s = ok ? sc[nt][reg] * 0.125f : -1e30f;
      v[nt] = s;
      m = fmaxf(m, s);
    }
#pragma unroll
    for (int off = 1; off <= 8; off <<= 1) m = fmaxf(m, __shfl_xor(m, off));
    float sum = 0.f;
#pragma unroll
    for (int nt = 0; nt < 12; nt++) {
      float p = __expf(v[nt] - m);
      v[nt] = p;
      sum += p;
    }
#pragma unroll
    for (int off = 1; off <= 8; off <<= 1) sum += __shfl_xor(sum, off);
    float inv = 1.0f / sum;
#pragma unroll
    for (int nt = 0; nt < 12; nt++)
      myP[(quad * 4 + reg) * 200 + nt * 16 + l16] = f2bf(v[nt] * inv);
  }
  __syncthreads();

  // PV: D[q][d] = sum_key P[q,key] * V[key][d]
  floatx4 oc[4] = {};
#pragma unroll
  for (int ks = 0; ks < 6; ks++) {
    bf16x8 ap = *(const bf16x8*)(myP + l16 * 200 + ks * 32 + quad * 8);
#pragma unroll
    for (int nt = 0; nt < 4; nt++) {
      bf16x8 bv = *(const bf16x8*)(sVt + (nt * 16 + l16) * 200 + ks * 32 + quad * 8);
      oc[nt] = MFMA16(ap, bv, oc[nt]);
    }
  }

  int srow = c * 64 + wave * 16 + quad * 4;
#pragma unroll
  for (int nt = 0; nt < 4; nt++) {
    u16* dp = ctx + (size_t)(b * S0 + srow) * HID + h * HD + nt * 16 + l16;
#pragma unroll
    for (int reg = 0; reg < 4; reg++)
      dp[(size_t)reg * HID] = f2bf(oc[nt][reg]);
  }
}

// ---------------------------------------------------------------------------
extern "C" void kernel_launch(void* const* d_in, const int* in_sizes, int n_in,
                              void* d_out, int out_size, void* d_ws, size_t ws_size,
                              hipStream_t stream) {
  const float* X = (const float*)d_in[0];
  const float* mask = (const float*)d_in[1];
  const float* Wq = (const float*)d_in[2];
  const float* bq = (const float*)d_in[3];
  const float* Wk = (const float*)d_in[4];
  const float* bk = (const float*)d_in[5];
  const float* Wv = (const float*)d_in[6];
  const float* bv = (const float*)d_in[7];
  const float* Wo = (const float*)d_in[8];
  const float* bo = (const float*)d_in[9];
  char* ws = (char*)d_ws;

  const size_t MB = 1048576;
  u16* cmask = (u16*)(ws + 256);               // 8192*2 = 16 KB
  u16* cb = (u16*)(ws + 256 + 16384);          // 4*1024*2 = 8 KB
  u16* cX = (u16*)(ws + 1 * MB);               // 16 MB (CTX aliases after gemm0)
  u16* WqkvT = (u16*)(ws + 17 * MB);           // 6 MB
  u16* WoT = (u16*)(ws + 23 * MB);             // 2 MB
  u16* QKV = (u16*)(ws + 25 * MB);             // 48 MB
  u16* CTX = cX;                               // alias: cX dead after gemm0

  const size_t per_qkv = (size_t)B_ * NH * S0 * HD;  // elements per Q/K/V

  convert_x<<<4096, 256, 0, stream>>>(X, cX);
  convert_small<<<48, 256, 0, stream>>>(mask, bq, bk, bv, bo, cmask, cb);
  transpose4<<<dim3(16, 16, 4), 256, 0, stream>>>(Wq, Wk, Wv, Wo, WqkvT, WoT);
  gemm_bf16_tn<<<dim3(64, 24), 256, 0, stream>>>(cX, WqkvT, cb, QKV, HID, 0);
  attn_win<<<dim3(B_ * NH * 64), 256, 0, stream>>>(QKV, QKV + per_qkv,
                                                   QKV + 2 * per_qkv, cmask, CTX);
  gemm_bf16_tn<<<dim3(64, 8), 256, 0, stream>>>(CTX, WoT, cb, d_out, HID, 1);
}

// Round 5
// 261.180 us; speedup vs baseline: 1.0058x; 1.0058x over previous
//
#include <hip/hip_runtime.h>

typedef unsigned short u16;
typedef unsigned int u32;
typedef __bf16 bf16x8 __attribute__((ext_vector_type(8)));
typedef u16 u16x8 __attribute__((ext_vector_type(8)));
typedef float floatx4 __attribute__((ext_vector_type(4)));

#define MFMA16(a, b, c) __builtin_amdgcn_mfma_f32_16x16x32_bf16((a), (b), (c), 0, 0, 0)

#define B_ 2
#define S0 4096
#define NH 16
#define HD 64
#define HID 1024

__device__ __forceinline__ float bf2f(u16 u) {
  union { u32 i; float f; } x; x.i = ((u32)u) << 16; return x.f;
}
__device__ __forceinline__ u16 f2bf(float f) {
  union { float f; u32 i; } x; x.f = f;
  u32 r = x.i + 0x7FFFu + ((x.i >> 16) & 1u);
  return (u16)(r >> 16);
}

__device__ __forceinline__ void glds16(const u16* g, u16* l) {
  __builtin_amdgcn_global_load_lds(
      (const __attribute__((address_space(1))) u32*)g,
      (__attribute__((address_space(3))) u32*)l, 16, 0, 0);
}

// -------- X (fp32) -> bf16 --------------------------------------------------
__global__ __launch_bounds__(256) void convert_x(const float* __restrict__ X,
                                                 u16* __restrict__ dst) {
  int i = (blockIdx.x * 256 + threadIdx.x) * 8;
  u16x8 v;
#pragma unroll
  for (int j = 0; j < 8; j++) v[j] = f2bf(X[i + j]);
  *(u16x8*)(dst + i) = v;
}

// -------- mask + 4 biases (fp32) -> bf16 ------------------------------------
__global__ __launch_bounds__(256) void convert_small(
    const float* __restrict__ mask, const float* __restrict__ bq,
    const float* __restrict__ bk, const float* __restrict__ bv,
    const float* __restrict__ bo, u16* __restrict__ cmask,
    u16* __restrict__ cb) {
  int tid = blockIdx.x * 256 + threadIdx.x;
  if (tid < B_ * S0) {
    cmask[tid] = f2bf(mask[tid]);
  } else {
    int j = tid - B_ * S0;  // [0, 4096)
    int seg = j >> 10, idx = j & 1023;
    const float* src = (seg == 0) ? bq : (seg == 1) ? bk : (seg == 2) ? bv : bo;
    cb[seg * 1024 + idx] = f2bf(src[idx]);
  }
}

// -------- weight transpose: W[k][n] (fp32) -> Wt[n][k] (bf16), 4 matrices ---
__global__ __launch_bounds__(256) void transpose4(
    const float* __restrict__ Wq, const float* __restrict__ Wk,
    const float* __restrict__ Wv, const float* __restrict__ Wo,
    u16* __restrict__ WqkvT, u16* __restrict__ WoT) {
  __shared__ u16 tile[64][66];
  int mat = blockIdx.z;
  const float* src = (mat == 0) ? Wq : (mat == 1) ? Wk : (mat == 2) ? Wv : Wo;
  u16* dst = (mat < 3) ? (WqkvT + (size_t)mat * HID * HID) : WoT;
  int t0 = blockIdx.x * 64;  // k base
  int c0 = blockIdx.y * 64;  // n base
  int tx = threadIdx.x & 63, ty = threadIdx.x >> 6;
#pragma unroll
  for (int i = 0; i < 16; i++) {
    int r = i * 4 + ty;
    tile[r][tx] = f2bf(src[(size_t)(t0 + r) * HID + c0 + tx]);
  }
  __syncthreads();
#pragma unroll
  for (int i = 0; i < 16; i++) {
    int r = i * 4 + ty;
    dst[(size_t)(c0 + r) * HID + t0 + tx] = tile[tx][r];
  }
}

// ---------------- bf16 GEMM: C[m][n] = A[m][k] * Bt[n][k] + bias -----------
// m97-style: global_load_lds width-16 staging.
// mode 0: N=3072 fused QKV, scatter bf16 to qkv[p][b][h][s][d] + bias cb[0..2]
// mode 1: N=1024, write fp32 row-major out + bias cb[3]
__global__ __launch_bounds__(256) void gemm_bf16_tn(
    const u16* __restrict__ A, const u16* __restrict__ Bt,
    const u16* __restrict__ cb, void* __restrict__ outp, int K, int mode) {
  __shared__ alignas(16) u16 sA[128 * 32];
  __shared__ alignas(16) u16 sB[128 * 32];
  int t = threadIdx.x;
  int wave = t >> 6, lane = t & 63;
  int wm = wave >> 1, wn = wave & 1;
  int quad = lane >> 4, l16 = lane & 15;
  int tile_m = blockIdx.x * 128;
  int tile_n = blockIdx.y * 128;

  floatx4 acc[4][4] = {};

  int srow = wave * 16 + (lane >> 2);   // row within 64-row half-tile
  int scol = (lane & 3) * 8;            // k offset within 32-wide K-slab
  const u16* Ag = A + (size_t)(tile_m + srow) * K + scol;
  const u16* Bg = Bt + (size_t)(tile_n + srow) * K + scol;
  u16* lA0 = sA + wave * 512;           // wave-uniform LDS base; HW adds lane*16B
  u16* lA1 = sA + 2048 + wave * 512;
  u16* lB0 = sB + wave * 512;
  u16* lB1 = sB + 2048 + wave * 512;
  size_t half = (size_t)64 * K;

  for (int k0 = 0; k0 < K; k0 += 32) {
    __syncthreads();  // previous slab's fragment reads done
    glds16(Ag + k0, lA0);
    glds16(Ag + half + k0, lA1);
    glds16(Bg + k0, lB0);
    glds16(Bg + half + k0, lB1);
    __syncthreads();  // drains vmcnt: staged data visible

    bf16x8 af[4], bfr[4];
#pragma unroll
    for (int mt = 0; mt < 4; mt++)
      af[mt] = *(const bf16x8*)(sA + (wm * 64 + mt * 16 + l16) * 32 + quad * 8);
#pragma unroll
    for (int nt = 0; nt < 4; nt++)
      bfr[nt] = *(const bf16x8*)(sB + (wn * 64 + nt * 16 + l16) * 32 + quad * 8);
#pragma unroll
    for (int mt = 0; mt < 4; mt++)
#pragma unroll
      for (int nt = 0; nt < 4; nt++)
        acc[mt][nt] = MFMA16(af[mt], bfr[nt], acc[mt][nt]);
  }

  if (mode == 0) {
    u16* op = (u16*)outp;
#pragma unroll
    for (int mt = 0; mt < 4; mt++) {
      int row0 = tile_m + wm * 64 + mt * 16 + quad * 4;
      int bb = row0 >> 12;
      int sbase = row0 & (S0 - 1);
#pragma unroll
      for (int nt = 0; nt < 4; nt++) {
        int col = tile_n + wn * 64 + nt * 16 + l16;
        int p = col >> 10;
        int rem = col & 1023;
        float bias = bf2f(cb[p * 1024 + rem]);
        int hh = rem >> 6, dd = rem & 63;
        u16* dp = op + ((size_t)(((p * 2 + bb) * NH + hh)) * S0 + sbase) * HD + dd;
#pragma unroll
        for (int r = 0; r < 4; r++)
          dp[(size_t)r * HD] = f2bf(acc[mt][nt][r] + bias);
      }
    }
  } else {
    float* op = (float*)outp;
#pragma unroll
    for (int mt = 0; mt < 4; mt++) {
      int row0 = tile_m + wm * 64 + mt * 16 + quad * 4;
#pragma unroll
      for (int nt = 0; nt < 4; nt++) {
        int col = tile_n + wn * 64 + nt * 16 + l16;
        float bias = bf2f(cb[3 * 1024 + col]);
        float* dp = op + (size_t)row0 * HID + col;
#pragma unroll
        for (int r = 0; r < 4; r++)
          dp[(size_t)r * HID] = acc[mt][nt][r] + bias;  // fp32 output
      }
    }
  }
}

// ---------------- windowed attention: one block per (b, h, chunk) ----------
// Per-wave key window: wave w needs keys [w*16, w*16+144) rel kbase;
// we process 10 16-key tiles = [w*16, w*16+160) (out-of-band cells -> P=0).
__global__ __launch_bounds__(256) void attn_win(
    const u16* __restrict__ Q, const u16* __restrict__ Kp,
    const u16* __restrict__ Vp, const u16* __restrict__ cmask,
    u16* __restrict__ ctx) {
  __shared__ alignas(16) u16 sVt[64 * 208];      // [d][key 0..207], stride 208
  __shared__ alignas(16) u16 sP[4 * 16 * 200];   // [wave][qrow][key window 160]
  __shared__ u16 sMk[208];

  int bid = blockIdx.x;
  int c = bid & 63;
  int h = (bid >> 6) & 15;
  int b = bid >> 10;
  int t = threadIdx.x;
  int wave = t >> 6, lane = t & 63;
  int quad = lane >> 4, l16 = lane & 15;
  int koff = wave * 16;  // this wave's key-window start (rel kbase)

  const u16* Qb = Q + (size_t)(b * NH + h) * S0 * HD;
  const u16* Kb = Kp + (size_t)(b * NH + h) * S0 * HD;
  const u16* Vb = Vp + (size_t)(b * NH + h) * S0 * HD;
  int kbase = (c - 1) * 64;  // global key index of slot 0

  // stage V^T into LDS: slots 0..207, vectorized 16B loads, scalar LDS scatter
#pragma unroll
  for (int i = 0; i < 7; i++) {
    int e = i * 256 + t;                 // 208*8 = 1664 tasks
    if (e < 1664) {
      int slot = e >> 3, d0 = (e & 7) * 8;
      int key = kbase + slot;
      int kc = key < 0 ? 0 : (key > S0 - 1 ? S0 - 1 : key);
      u16x8 v = *(const u16x8*)(Vb + (size_t)kc * HD + d0);
#pragma unroll
      for (int j = 0; j < 8; j++) sVt[(d0 + j) * 208 + slot] = v[j];
    }
  }
  if (t < 208) {
    int j = kbase + t;
    sMk[t] = (j >= 0 && j < S0) ? cmask[(size_t)b * S0 + j] : (u16)0;
  }
  __syncthreads();

  // scores: D[q][key], fragments direct from global (L1 shared across waves)
  floatx4 sc[10] = {};
  int qrow = c * 64 + wave * 16 + l16;
#pragma unroll
  for (int ks = 0; ks < 2; ks++) {
    bf16x8 aq = *(const bf16x8*)(Qb + (size_t)qrow * HD + ks * 32 + quad * 8);
#pragma unroll
    for (int nt = 0; nt < 10; nt++) {
      int key = kbase + koff + nt * 16 + l16;
      int kc = key < 0 ? 0 : (key > S0 - 1 ? S0 - 1 : key);
      bf16x8 bk = *(const bf16x8*)(Kb + (size_t)kc * HD + ks * 32 + quad * 8);
      sc[nt] = MFMA16(aq, bk, sc[nt]);
    }
  }

  // mask + softmax (rows across the 16 lanes of a quad) + write P
  int qrel_base = wave * 16 + quad * 4;
  u16* myP = sP + wave * 16 * 200;
  float kmask[10];
#pragma unroll
  for (int nt = 0; nt < 10; nt++) kmask[nt] = bf2f(sMk[koff + nt * 16 + l16]);

#pragma unroll
  for (int reg = 0; reg < 4; reg++) {
    int qrel = qrel_base + reg;
    float v[10];
    float m = -3e38f;
#pragma unroll
    for (int nt = 0; nt < 10; nt++) {
      int jr = koff + nt * 16 + l16 - 64;  // key rel. chunk start
      bool ok = (jr >= qrel - 64) && (jr <= qrel + 64) && (kmask[nt] > 0.f);
      float s = ok ? sc[nt][reg] * 0.125f : -1e30f;
      v[nt] = s;
      m = fmaxf(m, s);
    }
#pragma unroll
    for (int off = 1; off <= 8; off <<= 1) m = fmaxf(m, __shfl_xor(m, off));
    float sum = 0.f;
#pragma unroll
    for (int nt = 0; nt < 10; nt++) {
      float p = __expf(v[nt] - m);
      v[nt] = p;
      sum += p;
    }
#pragma unroll
    for (int off = 1; off <= 8; off <<= 1) sum += __shfl_xor(sum, off);
    float inv = 1.0f / sum;
#pragma unroll
    for (int nt = 0; nt < 10; nt++)
      myP[(quad * 4 + reg) * 200 + nt * 16 + l16] = f2bf(v[nt] * inv);
  }
  __syncthreads();

  // PV over the 160-key window: D[q][d] = sum_key P[q,key] * V[key][d]
  floatx4 oc[4] = {};
#pragma unroll
  for (int ks = 0; ks < 5; ks++) {
    bf16x8 ap = *(const bf16x8*)(myP + l16 * 200 + ks * 32 + quad * 8);
#pragma unroll
    for (int nt = 0; nt < 4; nt++) {
      bf16x8 bv =
          *(const bf16x8*)(sVt + (nt * 16 + l16) * 208 + koff + ks * 32 + quad * 8);
      oc[nt] = MFMA16(ap, bv, oc[nt]);
    }
  }

  int srow = c * 64 + wave * 16 + quad * 4;
#pragma unroll
  for (int nt = 0; nt < 4; nt++) {
    u16* dp = ctx + (size_t)(b * S0 + srow) * HID + h * HD + nt * 16 + l16;
#pragma unroll
    for (int reg = 0; reg < 4; reg++)
      dp[(size_t)reg * HID] = f2bf(oc[nt][reg]);
  }
}

// ---------------------------------------------------------------------------
extern "C" void kernel_launch(void* const* d_in, const int* in_sizes, int n_in,
                              void* d_out, int out_size, void* d_ws, size_t ws_size,
                              hipStream_t stream) {
  const float* X = (const float*)d_in[0];
  const float* mask = (const float*)d_in[1];
  const float* Wq = (const float*)d_in[2];
  const float* bq = (const float*)d_in[3];
  const float* Wk = (const float*)d_in[4];
  const float* bk = (const float*)d_in[5];
  const float* Wv = (const float*)d_in[6];
  const float* bv = (const float*)d_in[7];
  const float* Wo = (const float*)d_in[8];
  const float* bo = (const float*)d_in[9];
  char* ws = (char*)d_ws;

  const size_t MB = 1048576;
  u16* cmask = (u16*)(ws + 256);               // 16 KB
  u16* cb = (u16*)(ws + 256 + 16384);          // 8 KB
  u16* cX = (u16*)(ws + 1 * MB);               // 16 MB (CTX aliases after gemm0)
  u16* WqkvT = (u16*)(ws + 17 * MB);           // 6 MB
  u16* WoT = (u16*)(ws + 23 * MB);             // 2 MB
  u16* QKV = (u16*)(ws + 25 * MB);             // 48 MB
  u16* CTX = cX;                               // alias: cX dead after gemm0

  const size_t per_qkv = (size_t)B_ * NH * S0 * HD;  // elements per Q/K/V

  convert_x<<<4096, 256, 0, stream>>>(X, cX);
  convert_small<<<48, 256, 0, stream>>>(mask, bq, bk, bv, bo, cmask, cb);
  transpose4<<<dim3(16, 16, 4), 256, 0, stream>>>(Wq, Wk, Wv, Wo, WqkvT, WoT);
  gemm_bf16_tn<<<dim3(64, 24), 256, 0, stream>>>(cX, WqkvT, cb, QKV, HID, 0);
  attn_win<<<dim3(B_ * NH * 64), 256, 0, stream>>>(QKV, QKV + per_qkv,
                                                   QKV + 2 * per_qkv, cmask, CTX);
  gemm_bf16_tn<<<dim3(64, 8), 256, 0, stream>>>(CTX, WoT, cb, d_out, HID, 1);
}

// Round 6
// 234.778 us; speedup vs baseline: 1.1189x; 1.1125x over previous
//
#include <hip/hip_runtime.h>

typedef unsigned short u16;
typedef unsigned int u32;
typedef __bf16 bf16x8 __attribute__((ext_vector_type(8)));
typedef u16 u16x8 __attribute__((ext_vector_type(8)));
typedef float floatx4 __attribute__((ext_vector_type(4)));

#define MFMA16(a, b, c) __builtin_amdgcn_mfma_f32_16x16x32_bf16((a), (b), (c), 0, 0, 0)

#define B_ 2
#define S0 4096
#define NH 16
#define HD 64
#define HID 1024

__device__ __forceinline__ float bf2f(u16 u) {
  union { u32 i; float f; } x; x.i = ((u32)u) << 16; return x.f;
}
__device__ __forceinline__ u16 f2bf(float f) {
  union { float f; u32 i; } x; x.f = f;
  u32 r = x.i + 0x7FFFu + ((x.i >> 16) & 1u);
  return (u16)(r >> 16);
}

__device__ __forceinline__ void glds16(const u16* g, u16* l) {
  __builtin_amdgcn_global_load_lds(
      (const __attribute__((address_space(1))) u32*)g,
      (__attribute__((address_space(3))) u32*)l, 16, 0, 0);
}

// -------- fused prep: convert X, convert mask+biases, transpose weights -----
__global__ __launch_bounds__(256) void prep(
    const float* __restrict__ X, const float* __restrict__ mask,
    const float* __restrict__ Wq, const float* __restrict__ bq,
    const float* __restrict__ Wk, const float* __restrict__ bk,
    const float* __restrict__ Wv, const float* __restrict__ bv,
    const float* __restrict__ Wo, const float* __restrict__ bo,
    u16* __restrict__ cX, u16* __restrict__ cmask, u16* __restrict__ cb,
    u16* __restrict__ WqkvT, u16* __restrict__ WoT) {
  __shared__ u16 tile[64][66];
  int bid = blockIdx.x;
  if (bid < 4096) {                       // ---- X fp32 -> bf16 (8 elem/thr)
    int i = (bid * 256 + threadIdx.x) * 8;
    u16x8 v;
#pragma unroll
    for (int j = 0; j < 8; j++) v[j] = f2bf(X[i + j]);
    *(u16x8*)(cX + i) = v;
  } else if (bid < 4144) {                // ---- mask + biases
    int tid = (bid - 4096) * 256 + threadIdx.x;
    if (tid < B_ * S0) {
      cmask[tid] = f2bf(mask[tid]);
    } else {
      int j = tid - B_ * S0;  // [0, 4096)
      int seg = j >> 10, idx = j & 1023;
      const float* src = (seg == 0) ? bq : (seg == 1) ? bk : (seg == 2) ? bv : bo;
      cb[seg * 1024 + idx] = f2bf(src[idx]);
    }
  } else {                                // ---- weight transpose (1024 blocks)
    int idx = bid - 4144;
    int mat = idx >> 8;
    const float* src = (mat == 0) ? Wq : (mat == 1) ? Wk : (mat == 2) ? Wv : Wo;
    u16* dst = (mat < 3) ? (WqkvT + (size_t)mat * HID * HID) : WoT;
    int t0 = ((idx >> 4) & 15) * 64;  // k base
    int c0 = (idx & 15) * 64;         // n base
    int tx = threadIdx.x & 63, ty = threadIdx.x >> 6;
#pragma unroll
    for (int i = 0; i < 16; i++) {
      int r = i * 4 + ty;
      tile[r][tx] = f2bf(src[(size_t)(t0 + r) * HID + c0 + tx]);
    }
    __syncthreads();
#pragma unroll
    for (int i = 0; i < 16; i++) {
      int r = i * 4 + ty;
      dst[(size_t)(c0 + r) * HID + t0 + tx] = tile[tx][r];
    }
  }
}

// ---------------- bf16 GEMM: C[m][n] = A[m][k] * Bt[n][k] + bias -----------
// BK=64, glds16 staging, 16B-chunk XOR swizzle (p = c ^ (row&7)) for
// conflict-free ds_read_b128 fragment loads.
// mode 0: N=3072 fused QKV, scatter bf16 to qkv[p][b][h][s][d] + bias cb[0..2]
// mode 1: N=1024, write fp32 row-major out + bias cb[3]
__global__ __launch_bounds__(256) void gemm_bf16_tn(
    const u16* __restrict__ A, const u16* __restrict__ Bt,
    const u16* __restrict__ cb, void* __restrict__ outp, int K, int mode) {
  __shared__ alignas(16) u16 sA[128 * 64];
  __shared__ alignas(16) u16 sB[128 * 64];
  int t = threadIdx.x;
  int wave = t >> 6, lane = t & 63;
  int wm = wave >> 1, wn = wave & 1;
  int quad = lane >> 4, l16 = lane & 15;
  int tile_m = blockIdx.x * 128;
  int tile_n = blockIdx.y * 128;

  floatx4 acc[4][4] = {};

  // staging: wave w, rep r covers rows [r*32+w*8, +8) x 64 cols.
  // lane: row += l>>3; global col chunk c = (l&7) ^ (l>>3)  (swizzle source)
  int row_l = lane >> 3;
  int col_l = ((lane & 7) ^ row_l) * 8;
  const u16* Ag = A + (size_t)(tile_m + wave * 8 + row_l) * K + col_l;
  const u16* Bg = Bt + (size_t)(tile_n + wave * 8 + row_l) * K + col_l;
  u16* lA = sA + wave * 8 * 64;  // + r*2048; HW adds lane*16B
  u16* lB = sB + wave * 8 * 64;

  for (int k0 = 0; k0 < K; k0 += 64) {
    __syncthreads();  // previous slab's fragment reads done
#pragma unroll
    for (int r = 0; r < 4; r++) {
      glds16(Ag + (size_t)(r * 32) * K + k0, lA + r * 2048);
      glds16(Bg + (size_t)(r * 32) * K + k0, lB + r * 2048);
    }
    __syncthreads();  // drains vmcnt: staged data visible

#pragma unroll
    for (int ks = 0; ks < 2; ks++) {
      bf16x8 af[4], bfr[4];
#pragma unroll
      for (int mt = 0; mt < 4; mt++) {
        int row = wm * 64 + mt * 16 + l16;
        int p = (ks * 4 + quad) ^ (row & 7);  // un-swizzle
        af[mt] = *(const bf16x8*)(sA + row * 64 + p * 8);
      }
#pragma unroll
      for (int nt = 0; nt < 4; nt++) {
        int row = wn * 64 + nt * 16 + l16;
        int p = (ks * 4 + quad) ^ (row & 7);
        bfr[nt] = *(const bf16x8*)(sB + row * 64 + p * 8);
      }
#pragma unroll
      for (int mt = 0; mt < 4; mt++)
#pragma unroll
        for (int nt = 0; nt < 4; nt++)
          acc[mt][nt] = MFMA16(af[mt], bfr[nt], acc[mt][nt]);
    }
  }

  if (mode == 0) {
    u16* op = (u16*)outp;
#pragma unroll
    for (int mt = 0; mt < 4; mt++) {
      int row0 = tile_m + wm * 64 + mt * 16 + quad * 4;
      int bb = row0 >> 12;
      int sbase = row0 & (S0 - 1);
#pragma unroll
      for (int nt = 0; nt < 4; nt++) {
        int col = tile_n + wn * 64 + nt * 16 + l16;
        int p = col >> 10;
        int rem = col & 1023;
        float bias = bf2f(cb[p * 1024 + rem]);
        int hh = rem >> 6, dd = rem & 63;
        u16* dp = op + ((size_t)(((p * 2 + bb) * NH + hh)) * S0 + sbase) * HD + dd;
#pragma unroll
        for (int r = 0; r < 4; r++)
          dp[(size_t)r * HD] = f2bf(acc[mt][nt][r] + bias);
      }
    }
  } else {
    float* op = (float*)outp;
#pragma unroll
    for (int mt = 0; mt < 4; mt++) {
      int row0 = tile_m + wm * 64 + mt * 16 + quad * 4;
#pragma unroll
      for (int nt = 0; nt < 4; nt++) {
        int col = tile_n + wn * 64 + nt * 16 + l16;
        float bias = bf2f(cb[3 * 1024 + col]);
        float* dp = op + (size_t)row0 * HID + col;
#pragma unroll
        for (int r = 0; r < 4; r++)
          dp[(size_t)r * HID] = acc[mt][nt][r] + bias;  // fp32 output
      }
    }
  }
}

// ---------------- windowed attention: one block per (b, h, chunk) ----------
// Per-wave key window: wave w processes keys [w*16, w*16+160) rel kbase.
__global__ __launch_bounds__(256) void attn_win(
    const u16* __restrict__ Q, const u16* __restrict__ Kp,
    const u16* __restrict__ Vp, const u16* __restrict__ cmask,
    u16* __restrict__ ctx) {
  __shared__ alignas(16) u16 sVt[64 * 208];      // [d][key 0..207], stride 208
  __shared__ alignas(16) u16 sP[4 * 16 * 200];   // [wave][qrow][key window 160]
  __shared__ u16 sMk[208];

  int bid = blockIdx.x;
  int c = bid & 63;
  int h = (bid >> 6) & 15;
  int b = bid >> 10;
  int t = threadIdx.x;
  int wave = t >> 6, lane = t & 63;
  int quad = lane >> 4, l16 = lane & 15;
  int koff = wave * 16;  // this wave's key-window start (rel kbase)

  const u16* Qb = Q + (size_t)(b * NH + h) * S0 * HD;
  const u16* Kb = Kp + (size_t)(b * NH + h) * S0 * HD;
  const u16* Vb = Vp + (size_t)(b * NH + h) * S0 * HD;
  int kbase = (c - 1) * 64;  // global key index of slot 0

  // stage V^T: task e -> slot = e%208 (lane-consecutive => conflict-free LDS
  // writes), dgroup = e/208; each thread loads 16B of one V row.
#pragma unroll
  for (int i = 0; i < 7; i++) {
    int e = i * 256 + t;  // 208*8 = 1664 tasks
    if (e < 1664) {
      int dg = e / 208;        // 0..7 (d block of 8)
      int slot = e - dg * 208; // 0..207
      int key = kbase + slot;
      int kc = key < 0 ? 0 : (key > S0 - 1 ? S0 - 1 : key);
      u16x8 v = *(const u16x8*)(Vb + (size_t)kc * HD + dg * 8);
#pragma unroll
      for (int j = 0; j < 8; j++) sVt[(dg * 8 + j) * 208 + slot] = v[j];
    }
  }
  if (t < 208) {
    int j = kbase + t;
    sMk[t] = (j >= 0 && j < S0) ? cmask[(size_t)b * S0 + j] : (u16)0;
  }
  __syncthreads();

  // scores: D[q][key], K fragments direct from global (L1 shared across waves)
  floatx4 sc[10] = {};
  int qrow = c * 64 + wave * 16 + l16;
#pragma unroll
  for (int ks = 0; ks < 2; ks++) {
    bf16x8 aq = *(const bf16x8*)(Qb + (size_t)qrow * HD + ks * 32 + quad * 8);
#pragma unroll
    for (int nt = 0; nt < 10; nt++) {
      int key = kbase + koff + nt * 16 + l16;
      int kc = key < 0 ? 0 : (key > S0 - 1 ? S0 - 1 : key);
      bf16x8 bk = *(const bf16x8*)(Kb + (size_t)kc * HD + ks * 32 + quad * 8);
      sc[nt] = MFMA16(aq, bk, sc[nt]);
    }
  }

  // mask + softmax (rows across the 16 lanes of a quad) + write P
  int qrel_base = wave * 16 + quad * 4;
  u16* myP = sP + wave * 16 * 200;
  float kmask[10];
#pragma unroll
  for (int nt = 0; nt < 10; nt++) kmask[nt] = bf2f(sMk[koff + nt * 16 + l16]);

#pragma unroll
  for (int reg = 0; reg < 4; reg++) {
    int qrel = qrel_base + reg;
    float v[10];
    float m = -3e38f;
#pragma unroll
    for (int nt = 0; nt < 10; nt++) {
      int jr = koff + nt * 16 + l16 - 64;  // key rel. chunk start
      bool ok = (jr >= qrel - 64) && (jr <= qrel + 64) && (kmask[nt] > 0.f);
      float s = ok ? sc[nt][reg] * 0.125f : -1e30f;
      v[nt] = s;
      m = fmaxf(m, s);
    }
#pragma unroll
    for (int off = 1; off <= 8; off <<= 1) m = fmaxf(m, __shfl_xor(m, off));
    float sum = 0.f;
#pragma unroll
    for (int nt = 0; nt < 10; nt++) {
      float p = __expf(v[nt] - m);
      v[nt] = p;
      sum += p;
    }
#pragma unroll
    for (int off = 1; off <= 8; off <<= 1) sum += __shfl_xor(sum, off);
    float inv = 1.0f / sum;
#pragma unroll
    for (int nt = 0; nt < 10; nt++)
      myP[(quad * 4 + reg) * 200 + nt * 16 + l16] = f2bf(v[nt] * inv);
  }
  __syncthreads();

  // PV over the 160-key window: D[q][d] = sum_key P[q,key] * V[key][d]
  floatx4 oc[4] = {};
#pragma unroll
  for (int ks = 0; ks < 5; ks++) {
    bf16x8 ap = *(const bf16x8*)(myP + l16 * 200 + ks * 32 + quad * 8);
#pragma unroll
    for (int nt = 0; nt < 4; nt++) {
      bf16x8 bv =
          *(const bf16x8*)(sVt + (nt * 16 + l16) * 208 + koff + ks * 32 + quad * 8);
      oc[nt] = MFMA16(ap, bv, oc[nt]);
    }
  }

  int srow = c * 64 + wave * 16 + quad * 4;
#pragma unroll
  for (int nt = 0; nt < 4; nt++) {
    u16* dp = ctx + (size_t)(b * S0 + srow) * HID + h * HD + nt * 16 + l16;
#pragma unroll
    for (int reg = 0; reg < 4; reg++)
      dp[(size_t)reg * HID] = f2bf(oc[nt][reg]);
  }
}

// ---------------------------------------------------------------------------
extern "C" void kernel_launch(void* const* d_in, const int* in_sizes, int n_in,
                              void* d_out, int out_size, void* d_ws, size_t ws_size,
                              hipStream_t stream) {
  const float* X = (const float*)d_in[0];
  const float* mask = (const float*)d_in[1];
  const float* Wq = (const float*)d_in[2];
  const float* bq = (const float*)d_in[3];
  const float* Wk = (const float*)d_in[4];
  const float* bk = (const float*)d_in[5];
  const float* Wv = (const float*)d_in[6];
  const float* bv = (const float*)d_in[7];
  const float* Wo = (const float*)d_in[8];
  const float* bo = (const float*)d_in[9];
  char* ws = (char*)d_ws;

  const size_t MB = 1048576;
  u16* cmask = (u16*)(ws + 256);               // 16 KB
  u16* cb = (u16*)(ws + 256 + 16384);          // 8 KB
  u16* cX = (u16*)(ws + 1 * MB);               // 16 MB (CTX aliases after gemm0)
  u16* WqkvT = (u16*)(ws + 17 * MB);           // 6 MB
  u16* WoT = (u16*)(ws + 23 * MB);             // 2 MB
  u16* QKV = (u16*)(ws + 25 * MB);             // 48 MB
  u16* CTX = cX;                               // alias: cX dead after gemm0

  const size_t per_qkv = (size_t)B_ * NH * S0 * HD;  // elements per Q/K/V

  prep<<<4096 + 48 + 1024, 256, 0, stream>>>(X, mask, Wq, bq, Wk, bk, Wv, bv,
                                             Wo, bo, cX, cmask, cb, WqkvT, WoT);
  gemm_bf16_tn<<<dim3(64, 24), 256, 0, stream>>>(cX, WqkvT, cb, QKV, HID, 0);
  attn_win<<<dim3(B_ * NH * 64), 256, 0, stream>>>(QKV, QKV + per_qkv,
                                                   QKV + 2 * per_qkv, cmask, CTX);
  gemm_bf16_tn<<<dim3(64, 8), 256, 0, stream>>>(CTX, WoT, cb, d_out, HID, 1);
}

// Round 7
// 230.841 us; speedup vs baseline: 1.1380x; 1.0171x over previous
//
#include <hip/hip_runtime.h>

typedef unsigned short u16;
typedef unsigned int u32;
typedef __bf16 bf16x8 __attribute__((ext_vector_type(8)));
typedef u16 u16x8 __attribute__((ext_vector_type(8)));
typedef float floatx4 __attribute__((ext_vector_type(4)));

#define MFMA16(a, b, c) __builtin_amdgcn_mfma_f32_16x16x32_bf16((a), (b), (c), 0, 0, 0)

#define B_ 2
#define S0 4096
#define NH 16
#define HD 64
#define HID 1024

__device__ __forceinline__ float bf2f(u16 u) {
  union { u32 i; float f; } x; x.i = ((u32)u) << 16; return x.f;
}
__device__ __forceinline__ u16 f2bf(float f) {
  union { float f; u32 i; } x; x.f = f;
  u32 r = x.i + 0x7FFFu + ((x.i >> 16) & 1u);
  return (u16)(r >> 16);
}

__device__ __forceinline__ void glds16(const u16* g, u16* l) {
  __builtin_amdgcn_global_load_lds(
      (const __attribute__((address_space(1))) u32*)g,
      (__attribute__((address_space(3))) u32*)l, 16, 0, 0);
}

// -------- fused prep: convert X, convert mask+biases, transpose weights -----
__global__ __launch_bounds__(256) void prep(
    const float* __restrict__ X, const float* __restrict__ mask,
    const float* __restrict__ Wq, const float* __restrict__ bq,
    const float* __restrict__ Wk, const float* __restrict__ bk,
    const float* __restrict__ Wv, const float* __restrict__ bv,
    const float* __restrict__ Wo, const float* __restrict__ bo,
    u16* __restrict__ cX, u16* __restrict__ cmask, u16* __restrict__ cb,
    u16* __restrict__ WqkvT, u16* __restrict__ WoT) {
  __shared__ u16 tile[64][66];
  int bid = blockIdx.x;
  if (bid < 4096) {                       // ---- X fp32 -> bf16 (8 elem/thr)
    int i = (bid * 256 + threadIdx.x) * 8;
    u16x8 v;
#pragma unroll
    for (int j = 0; j < 8; j++) v[j] = f2bf(X[i + j]);
    *(u16x8*)(cX + i) = v;
  } else if (bid < 4144) {                // ---- mask + biases
    int tid = (bid - 4096) * 256 + threadIdx.x;
    if (tid < B_ * S0) {
      cmask[tid] = f2bf(mask[tid]);
    } else {
      int j = tid - B_ * S0;  // [0, 4096)
      int seg = j >> 10, idx = j & 1023;
      const float* src = (seg == 0) ? bq : (seg == 1) ? bk : (seg == 2) ? bv : bo;
      cb[seg * 1024 + idx] = f2bf(src[idx]);
    }
  } else {                                // ---- weight transpose (1024 blocks)
    int idx = bid - 4144;
    int mat = idx >> 8;
    const float* src = (mat == 0) ? Wq : (mat == 1) ? Wk : (mat == 2) ? Wv : Wo;
    u16* dst = (mat < 3) ? (WqkvT + (size_t)mat * HID * HID) : WoT;
    int t0 = ((idx >> 4) & 15) * 64;  // k base
    int c0 = (idx & 15) * 64;         // n base
    int tx = threadIdx.x & 63, ty = threadIdx.x >> 6;
#pragma unroll
    for (int i = 0; i < 16; i++) {
      int r = i * 4 + ty;
      tile[r][tx] = f2bf(src[(size_t)(t0 + r) * HID + c0 + tx]);
    }
    __syncthreads();
#pragma unroll
    for (int i = 0; i < 16; i++) {
      int r = i * 4 + ty;
      dst[(size_t)(c0 + r) * HID + t0 + tx] = tile[tx][r];
    }
  }
}

// ---------------- bf16 GEMM: C[m][n] = A[m][k] * Bt[n][k] + bias -----------
// BK=64, glds16 staging, 16B-chunk XOR swizzle -> conflict-free ds_read_b128.
// BN: 96 (mode 0, grid 64x32 = 8 blk/CU = 2 even phases) or 128 (mode 1).
// MODE 0: fused QKV, scatter bf16 to qkv[p][b][h][s][d] + bias cb[0..2]
// MODE 1: write fp32 row-major out + bias cb[3]
template <int BN, int MODE>
__global__ __launch_bounds__(256) void gemm_bf16_tn(
    const u16* __restrict__ A, const u16* __restrict__ Bt,
    const u16* __restrict__ cb, void* __restrict__ outp, int K) {
  constexpr int NT = BN / 32;  // 16-col tiles per wave (wave covers BN/2 cols)
  __shared__ alignas(16) u16 sA[128 * 64];
  __shared__ alignas(16) u16 sB[BN * 64];
  int t = threadIdx.x;
  int wave = t >> 6, lane = t & 63;
  int wm = wave >> 1, wn = wave & 1;
  int quad = lane >> 4, l16 = lane & 15;
  int tile_m = blockIdx.x * 128;
  int tile_n = blockIdx.y * BN;

  floatx4 acc[4][NT] = {};

  // staging: wave w, rep r covers rows [r*32+w*8, +8) x 64 cols.
  // lane: row += l>>3; global col chunk c = (l&7) ^ (l>>3)  (swizzle source)
  int row_l = lane >> 3;
  int col_l = ((lane & 7) ^ row_l) * 8;
  const u16* Ag = A + (size_t)(tile_m + wave * 8 + row_l) * K + col_l;
  const u16* Bg = Bt + (size_t)(tile_n + wave * 8 + row_l) * K + col_l;
  u16* lA = sA + wave * 8 * 64;  // + r*2048; HW adds lane*16B
  u16* lB = sB + wave * 8 * 64;

  for (int k0 = 0; k0 < K; k0 += 64) {
    __syncthreads();  // previous slab's fragment reads done
#pragma unroll
    for (int r = 0; r < 4; r++)
      glds16(Ag + (size_t)(r * 32) * K + k0, lA + r * 2048);
#pragma unroll
    for (int r = 0; r < BN / 32; r++)
      glds16(Bg + (size_t)(r * 32) * K + k0, lB + r * 2048);
    __syncthreads();  // drains vmcnt: staged data visible

#pragma unroll
    for (int ks = 0; ks < 2; ks++) {
      bf16x8 af[4], bfr[NT];
#pragma unroll
      for (int mt = 0; mt < 4; mt++) {
        int row = wm * 64 + mt * 16 + l16;
        int p = (ks * 4 + quad) ^ (row & 7);  // un-swizzle
        af[mt] = *(const bf16x8*)(sA + row * 64 + p * 8);
      }
#pragma unroll
      for (int nt = 0; nt < NT; nt++) {
        int row = wn * (BN / 2) + nt * 16 + l16;
        int p = (ks * 4 + quad) ^ (row & 7);
        bfr[nt] = *(const bf16x8*)(sB + row * 64 + p * 8);
      }
#pragma unroll
      for (int mt = 0; mt < 4; mt++)
#pragma unroll
        for (int nt = 0; nt < NT; nt++)
          acc[mt][nt] = MFMA16(af[mt], bfr[nt], acc[mt][nt]);
    }
  }

  if (MODE == 0) {
    u16* op = (u16*)outp;
#pragma unroll
    for (int mt = 0; mt < 4; mt++) {
      int row0 = tile_m + wm * 64 + mt * 16 + quad * 4;
      int bb = row0 >> 12;
      int sbase = row0 & (S0 - 1);
#pragma unroll
      for (int nt = 0; nt < NT; nt++) {
        int col = tile_n + wn * (BN / 2) + nt * 16 + l16;
        int p = col >> 10;
        int rem = col & 1023;
        float bias = bf2f(cb[p * 1024 + rem]);
        int hh = rem >> 6, dd = rem & 63;
        u16* dp = op + ((size_t)(((p * 2 + bb) * NH + hh)) * S0 + sbase) * HD + dd;
#pragma unroll
        for (int r = 0; r < 4; r++)
          dp[(size_t)r * HD] = f2bf(acc[mt][nt][r] + bias);
      }
    }
  } else {
    float* op = (float*)outp;
#pragma unroll
    for (int mt = 0; mt < 4; mt++) {
      int row0 = tile_m + wm * 64 + mt * 16 + quad * 4;
#pragma unroll
      for (int nt = 0; nt < NT; nt++) {
        int col = tile_n + wn * (BN / 2) + nt * 16 + l16;
        float bias = bf2f(cb[3 * 1024 + col]);
        float* dp = op + (size_t)row0 * HID + col;
#pragma unroll
        for (int r = 0; r < 4; r++)
          dp[(size_t)r * HID] = acc[mt][nt][r] + bias;  // fp32 output
      }
    }
  }
}

// ---------------- windowed attention: one block per (b, h, chunk) ----------
// Per-wave key window: wave w processes keys [w*16, w*16+160) rel kbase.
__global__ __launch_bounds__(256) void attn_win(
    const u16* __restrict__ Q, const u16* __restrict__ Kp,
    const u16* __restrict__ Vp, const u16* __restrict__ cmask,
    u16* __restrict__ ctx) {
  __shared__ alignas(16) u16 sVt[64 * 208];      // [d][key 0..207], stride 208
  __shared__ alignas(16) u16 sP[4 * 16 * 200];   // [wave][qrow][key window 160]
  __shared__ u16 sMk[208];

  int bid = blockIdx.x;
  int c = bid & 63;
  int h = (bid >> 6) & 15;
  int b = bid >> 10;
  int t = threadIdx.x;
  int wave = t >> 6, lane = t & 63;
  int quad = lane >> 4, l16 = lane & 15;
  int koff = wave * 16;  // this wave's key-window start (rel kbase)

  const u16* Qb = Q + (size_t)(b * NH + h) * S0 * HD;
  const u16* Kb = Kp + (size_t)(b * NH + h) * S0 * HD;
  const u16* Vb = Vp + (size_t)(b * NH + h) * S0 * HD;
  int kbase = (c - 1) * 64;  // global key index of slot 0

  // stage V^T: task e -> slot = e%208 (lane-consecutive => conflict-free LDS
  // writes), dgroup = e/208; each thread loads 16B of one V row.
#pragma unroll
  for (int i = 0; i < 7; i++) {
    int e = i * 256 + t;  // 208*8 = 1664 tasks
    if (e < 1664) {
      int dg = e / 208;        // 0..7 (d block of 8)
      int slot = e - dg * 208; // 0..207
      int key = kbase + slot;
      int kc = key < 0 ? 0 : (key > S0 - 1 ? S0 - 1 : key);
      u16x8 v = *(const u16x8*)(Vb + (size_t)kc * HD + dg * 8);
#pragma unroll
      for (int j = 0; j < 8; j++) sVt[(dg * 8 + j) * 208 + slot] = v[j];
    }
  }
  if (t < 208) {
    int j = kbase + t;
    sMk[t] = (j >= 0 && j < S0) ? cmask[(size_t)b * S0 + j] : (u16)0;
  }
  __syncthreads();

  // scores: D[q][key], K fragments direct from global (L1 shared across waves)
  floatx4 sc[10] = {};
  int qrow = c * 64 + wave * 16 + l16;
#pragma unroll
  for (int ks = 0; ks < 2; ks++) {
    bf16x8 aq = *(const bf16x8*)(Qb + (size_t)qrow * HD + ks * 32 + quad * 8);
#pragma unroll
    for (int nt = 0; nt < 10; nt++) {
      int key = kbase + koff + nt * 16 + l16;
      int kc = key < 0 ? 0 : (key > S0 - 1 ? S0 - 1 : key);
      bf16x8 bk = *(const bf16x8*)(Kb + (size_t)kc * HD + ks * 32 + quad * 8);
      sc[nt] = MFMA16(aq, bk, sc[nt]);
    }
  }

  // mask + softmax (rows across the 16 lanes of a quad) + write P
  int qrel_base = wave * 16 + quad * 4;
  u16* myP = sP + wave * 16 * 200;
  float kmask[10];
#pragma unroll
  for (int nt = 0; nt < 10; nt++) kmask[nt] = bf2f(sMk[koff + nt * 16 + l16]);

#pragma unroll
  for (int reg = 0; reg < 4; reg++) {
    int qrel = qrel_base + reg;
    float v[10];
    float m = -3e38f;
#pragma unroll
    for (int nt = 0; nt < 10; nt++) {
      int jr = koff + nt * 16 + l16 - 64;  // key rel. chunk start
      bool ok = (jr >= qrel - 64) && (jr <= qrel + 64) && (kmask[nt] > 0.f);
      float s = ok ? sc[nt][reg] * 0.125f : -1e30f;
      v[nt] = s;
      m = fmaxf(m, s);
    }
#pragma unroll
    for (int off = 1; off <= 8; off <<= 1) m = fmaxf(m, __shfl_xor(m, off));
    float sum = 0.f;
#pragma unroll
    for (int nt = 0; nt < 10; nt++) {
      float p = __expf(v[nt] - m);
      v[nt] = p;
      sum += p;
    }
#pragma unroll
    for (int off = 1; off <= 8; off <<= 1) sum += __shfl_xor(sum, off);
    float inv = 1.0f / sum;
#pragma unroll
    for (int nt = 0; nt < 10; nt++)
      myP[(quad * 4 + reg) * 200 + nt * 16 + l16] = f2bf(v[nt] * inv);
  }
  __syncthreads();

  // PV over the 160-key window: D[q][d] = sum_key P[q,key] * V[key][d]
  floatx4 oc[4] = {};
#pragma unroll
  for (int ks = 0; ks < 5; ks++) {
    bf16x8 ap = *(const bf16x8*)(myP + l16 * 200 + ks * 32 + quad * 8);
#pragma unroll
    for (int nt = 0; nt < 4; nt++) {
      bf16x8 bv =
          *(const bf16x8*)(sVt + (nt * 16 + l16) * 208 + koff + ks * 32 + quad * 8);
      oc[nt] = MFMA16(ap, bv, oc[nt]);
    }
  }

  int srow = c * 64 + wave * 16 + quad * 4;
#pragma unroll
  for (int nt = 0; nt < 4; nt++) {
    u16* dp = ctx + (size_t)(b * S0 + srow) * HID + h * HD + nt * 16 + l16;
#pragma unroll
    for (int reg = 0; reg < 4; reg++)
      dp[(size_t)reg * HID] = f2bf(oc[nt][reg]);
  }
}

// ---------------------------------------------------------------------------
extern "C" void kernel_launch(void* const* d_in, const int* in_sizes, int n_in,
                              void* d_out, int out_size, void* d_ws, size_t ws_size,
                              hipStream_t stream) {
  const float* X = (const float*)d_in[0];
  const float* mask = (const float*)d_in[1];
  const float* Wq = (const float*)d_in[2];
  const float* bq = (const float*)d_in[3];
  const float* Wk = (const float*)d_in[4];
  const float* bk = (const float*)d_in[5];
  const float* Wv = (const float*)d_in[6];
  const float* bv = (const float*)d_in[7];
  const float* Wo = (const float*)d_in[8];
  const float* bo = (const float*)d_in[9];
  char* ws = (char*)d_ws;

  const size_t MB = 1048576;
  u16* cmask = (u16*)(ws + 256);               // 16 KB
  u16* cb = (u16*)(ws + 256 + 16384);          // 8 KB
  u16* cX = (u16*)(ws + 1 * MB);               // 16 MB (CTX aliases after gemm0)
  u16* WqkvT = (u16*)(ws + 17 * MB);           // 6 MB
  u16* WoT = (u16*)(ws + 23 * MB);             // 2 MB
  u16* QKV = (u16*)(ws + 25 * MB);             // 48 MB
  u16* CTX = cX;                               // alias: cX dead after gemm0

  const size_t per_qkv = (size_t)B_ * NH * S0 * HD;  // elements per Q/K/V

  prep<<<4096 + 48 + 1024, 256, 0, stream>>>(X, mask, Wq, bq, Wk, bk, Wv, bv,
                                             Wo, bo, cX, cmask, cb, WqkvT, WoT);
  gemm_bf16_tn<96, 0><<<dim3(64, 32), 256, 0, stream>>>(cX, WqkvT, cb, QKV, HID);
  attn_win<<<dim3(B_ * NH * 64), 256, 0, stream>>>(QKV, QKV + per_qkv,
                                                   QKV + 2 * per_qkv, cmask, CTX);
  gemm_bf16_tn<128, 1><<<dim3(64, 8), 256, 0, stream>>>(CTX, WoT, cb, d_out, HID);
}

// Round 8
// 226.999 us; speedup vs baseline: 1.1573x; 1.0169x over previous
//
#include <hip/hip_runtime.h>

typedef unsigned short u16;
typedef unsigned int u32;
typedef __bf16 bf16x8 __attribute__((ext_vector_type(8)));
typedef u16 u16x8 __attribute__((ext_vector_type(8)));
typedef float floatx4 __attribute__((ext_vector_type(4)));

#define MFMA16(a, b, c) __builtin_amdgcn_mfma_f32_16x16x32_bf16((a), (b), (c), 0, 0, 0)

#define B_ 2
#define S0 4096
#define NH 16
#define HD 64
#define HID 1024

__device__ __forceinline__ float bf2f(u16 u) {
  union { u32 i; float f; } x; x.i = ((u32)u) << 16; return x.f;
}
__device__ __forceinline__ u16 f2bf(float f) {
  union { float f; u32 i; } x; x.f = f;
  u32 r = x.i + 0x7FFFu + ((x.i >> 16) & 1u);
  return (u16)(r >> 16);
}

__device__ __forceinline__ void glds16(const u16* g, u16* l) {
  __builtin_amdgcn_global_load_lds(
      (const __attribute__((address_space(1))) u32*)g,
      (__attribute__((address_space(3))) u32*)l, 16, 0, 0);
}

// -------- fused prep: convert X, convert mask+biases, transpose weights -----
__global__ __launch_bounds__(256) void prep(
    const float* __restrict__ X, const float* __restrict__ mask,
    const float* __restrict__ Wq, const float* __restrict__ bq,
    const float* __restrict__ Wk, const float* __restrict__ bk,
    const float* __restrict__ Wv, const float* __restrict__ bv,
    const float* __restrict__ Wo, const float* __restrict__ bo,
    u16* __restrict__ cX, u16* __restrict__ cmask, u16* __restrict__ cb,
    u16* __restrict__ WqkvT, u16* __restrict__ WoT) {
  __shared__ u16 tile[64][66];
  int bid = blockIdx.x;
  if (bid < 4096) {                       // ---- X fp32 -> bf16 (8 elem/thr)
    int i = (bid * 256 + threadIdx.x) * 8;
    u16x8 v;
#pragma unroll
    for (int j = 0; j < 8; j++) v[j] = f2bf(X[i + j]);
    *(u16x8*)(cX + i) = v;
  } else if (bid < 4144) {                // ---- mask + biases
    int tid = (bid - 4096) * 256 + threadIdx.x;
    if (tid < B_ * S0) {
      cmask[tid] = f2bf(mask[tid]);
    } else {
      int j = tid - B_ * S0;  // [0, 4096)
      int seg = j >> 10, idx = j & 1023;
      const float* src = (seg == 0) ? bq : (seg == 1) ? bk : (seg == 2) ? bv : bo;
      cb[seg * 1024 + idx] = f2bf(src[idx]);
    }
  } else {                                // ---- weight transpose (1024 blocks)
    int idx = bid - 4144;
    int mat = idx >> 8;
    const float* src = (mat == 0) ? Wq : (mat == 1) ? Wk : (mat == 2) ? Wv : Wo;
    u16* dst = (mat < 3) ? (WqkvT + (size_t)mat * HID * HID) : WoT;
    int t0 = ((idx >> 4) & 15) * 64;  // k base
    int c0 = (idx & 15) * 64;         // n base
    int tx = threadIdx.x & 63, ty = threadIdx.x >> 6;
#pragma unroll
    for (int i = 0; i < 16; i++) {
      int r = i * 4 + ty;
      tile[r][tx] = f2bf(src[(size_t)(t0 + r) * HID + c0 + tx]);
    }
    __syncthreads();
#pragma unroll
    for (int i = 0; i < 16; i++) {
      int r = i * 4 + ty;
      dst[(size_t)(c0 + r) * HID + t0 + tx] = tile[tx][r];
    }
  }
}

// ---------------- bf16 GEMM: C[m][n] = A[m][k] * Bt[n][k] + bias -----------
// BK=64, glds16 staging, 16B-chunk XOR swizzle -> conflict-free ds_read_b128.
// BN: 96 (mode 0, grid 64x32 = 8 blk/CU = 2 even phases) or 128 (mode 1).
template <int BN, int MODE>
__global__ __launch_bounds__(256) void gemm_bf16_tn(
    const u16* __restrict__ A, const u16* __restrict__ Bt,
    const u16* __restrict__ cb, void* __restrict__ outp, int K) {
  constexpr int NT = BN / 32;  // 16-col tiles per wave (wave covers BN/2 cols)
  __shared__ alignas(16) u16 sA[128 * 64];
  __shared__ alignas(16) u16 sB[BN * 64];
  int t = threadIdx.x;
  int wave = t >> 6, lane = t & 63;
  int wm = wave >> 1, wn = wave & 1;
  int quad = lane >> 4, l16 = lane & 15;
  int tile_m = blockIdx.x * 128;
  int tile_n = blockIdx.y * BN;

  floatx4 acc[4][NT] = {};

  int row_l = lane >> 3;
  int col_l = ((lane & 7) ^ row_l) * 8;
  const u16* Ag = A + (size_t)(tile_m + wave * 8 + row_l) * K + col_l;
  const u16* Bg = Bt + (size_t)(tile_n + wave * 8 + row_l) * K + col_l;
  u16* lA = sA + wave * 8 * 64;
  u16* lB = sB + wave * 8 * 64;

  for (int k0 = 0; k0 < K; k0 += 64) {
    __syncthreads();
#pragma unroll
    for (int r = 0; r < 4; r++)
      glds16(Ag + (size_t)(r * 32) * K + k0, lA + r * 2048);
#pragma unroll
    for (int r = 0; r < BN / 32; r++)
      glds16(Bg + (size_t)(r * 32) * K + k0, lB + r * 2048);
    __syncthreads();

#pragma unroll
    for (int ks = 0; ks < 2; ks++) {
      bf16x8 af[4], bfr[NT];
#pragma unroll
      for (int mt = 0; mt < 4; mt++) {
        int row = wm * 64 + mt * 16 + l16;
        int p = (ks * 4 + quad) ^ (row & 7);
        af[mt] = *(const bf16x8*)(sA + row * 64 + p * 8);
      }
#pragma unroll
      for (int nt = 0; nt < NT; nt++) {
        int row = wn * (BN / 2) + nt * 16 + l16;
        int p = (ks * 4 + quad) ^ (row & 7);
        bfr[nt] = *(const bf16x8*)(sB + row * 64 + p * 8);
      }
#pragma unroll
      for (int mt = 0; mt < 4; mt++)
#pragma unroll
        for (int nt = 0; nt < NT; nt++)
          acc[mt][nt] = MFMA16(af[mt], bfr[nt], acc[mt][nt]);
    }
  }

  if (MODE == 0) {
    u16* op = (u16*)outp;
#pragma unroll
    for (int mt = 0; mt < 4; mt++) {
      int row0 = tile_m + wm * 64 + mt * 16 + quad * 4;
      int bb = row0 >> 12;
      int sbase = row0 & (S0 - 1);
#pragma unroll
      for (int nt = 0; nt < NT; nt++) {
        int col = tile_n + wn * (BN / 2) + nt * 16 + l16;
        int p = col >> 10;
        int rem = col & 1023;
        float bias = bf2f(cb[p * 1024 + rem]);
        int hh = rem >> 6, dd = rem & 63;
        u16* dp = op + ((size_t)(((p * 2 + bb) * NH + hh)) * S0 + sbase) * HD + dd;
#pragma unroll
        for (int r = 0; r < 4; r++)
          dp[(size_t)r * HD] = f2bf(acc[mt][nt][r] + bias);
      }
    }
  } else {
    float* op = (float*)outp;
#pragma unroll
    for (int mt = 0; mt < 4; mt++) {
      int row0 = tile_m + wm * 64 + mt * 16 + quad * 4;
#pragma unroll
      for (int nt = 0; nt < NT; nt++) {
        int col = tile_n + wn * (BN / 2) + nt * 16 + l16;
        float bias = bf2f(cb[3 * 1024 + col]);
        float* dp = op + (size_t)row0 * HID + col;
#pragma unroll
        for (int r = 0; r < 4; r++)
          dp[(size_t)r * HID] = acc[mt][nt][r] + bias;  // fp32 output
      }
    }
  }
}

// ---------------- windowed attention: one block per (b, h, chunk) ----------
// Wave w covers queries [w*16, w*16+16) and keys [w*16, w*16+144) rel kbase
// (exactly the band). K staged in LDS (XOR-swizzled); same buffer re-staged
// as V^T for PV; V global loads issued before softmax to hide latency.
__global__ __launch_bounds__(256) void attn_win(
    const u16* __restrict__ Q, const u16* __restrict__ Kp,
    const u16* __restrict__ Vp, const u16* __restrict__ cmask,
    u16* __restrict__ ctx) {
  __shared__ alignas(16) u16 buf0[208 * 64];   // phase1: K swizzled [slot][64]
                                               // phase2: V^T [d][208]
  __shared__ alignas(16) u16 sP[4 * 16 * 200]; // [wave][qrow][key 0..160)
  __shared__ u16 sMk[208];

  int bid = blockIdx.x;
  int c = bid & 63;
  int h = (bid >> 6) & 15;
  int b = bid >> 10;
  int t = threadIdx.x;
  int wave = t >> 6, lane = t & 63;
  int quad = lane >> 4, l16 = lane & 15;
  int koff = wave * 16;  // this wave's key-window start (rel kbase)

  const u16* Qb = Q + (size_t)(b * NH + h) * S0 * HD;
  const u16* Kb = Kp + (size_t)(b * NH + h) * S0 * HD;
  const u16* Vb = Vp + (size_t)(b * NH + h) * S0 * HD;
  int kbase = (c - 1) * 64;  // global key index of slot 0

  // ---- stage K via glds16, source-swizzled (chunk csrc -> LDS chunk l&7) --
  int rrow = lane >> 3;                 // row within the wave's 8-row group
  int csrc = ((lane & 7) ^ rrow) * 8;   // swizzled source chunk (elems)
#pragma unroll
  for (int p = 0; p < 7; p++) {
    int sl0 = p * 32 + wave * 8;        // wave-uniform row base (mult of 8)
    if (sl0 < 208) {
      int key = kbase + sl0 + rrow;
      int kc = key < 0 ? 0 : (key > S0 - 1 ? S0 - 1 : key);
      glds16(Kb + (size_t)kc * HD + csrc, buf0 + sl0 * 64);
    }
  }
  if (t < 208) {
    int j = kbase + t;
    sMk[t] = (j >= 0 && j < S0) ? cmask[(size_t)b * S0 + j] : (u16)0;
  }
  __syncthreads();

  // ---- QK from LDS: 9 key tiles cover the band exactly --------------------
  floatx4 sc[9] = {};
  int qrow = c * 64 + wave * 16 + l16;
#pragma unroll
  for (int ks = 0; ks < 2; ks++) {
    bf16x8 aq = *(const bf16x8*)(Qb + (size_t)qrow * HD + ks * 32 + quad * 8);
#pragma unroll
    for (int nt = 0; nt < 9; nt++) {
      int slot = koff + nt * 16 + l16;
      int pch = ((ks * 4 + quad) ^ (l16 & 7)) * 8;  // un-swizzle
      bf16x8 bk = *(const bf16x8*)(buf0 + slot * 64 + pch);
      sc[nt] = MFMA16(aq, bk, sc[nt]);
    }
  }

  // ---- preload V into registers (latency hides under softmax) -------------
  u16x8 vreg[7];
#pragma unroll
  for (int i = 0; i < 7; i++) {
    int e = i * 256 + t;  // 208*8 = 1664 tasks
    if (e < 1664) {
      int dg = e / 208;         // d block of 8
      int slot = e - dg * 208;  // 0..207
      int key = kbase + slot;
      int kc = key < 0 ? 0 : (key > S0 - 1 ? S0 - 1 : key);
      vreg[i] = *(const u16x8*)(Vb + (size_t)kc * HD + dg * 8);
    }
  }

  // ---- mask + softmax (rows across the 16 lanes of a quad) + write P ------
  int qrel_base = wave * 16 + quad * 4;
  u16* myP = sP + wave * 16 * 200;
  float kmask[9];
#pragma unroll
  for (int nt = 0; nt < 9; nt++) kmask[nt] = bf2f(sMk[koff + nt * 16 + l16]);

#pragma unroll
  for (int reg = 0; reg < 4; reg++) {
    int qrel = qrel_base + reg;
    float v[9];
    float m = -3e38f;
#pragma unroll
    for (int nt = 0; nt < 9; nt++) {
      int slot = koff + nt * 16 + l16;  // band: qrel <= slot <= qrel+128
      bool ok = (slot >= qrel) && (slot <= qrel + 128) && (kmask[nt] > 0.f);
      float s = ok ? sc[nt][reg] * 0.125f : -1e30f;
      v[nt] = s;
      m = fmaxf(m, s);
    }
#pragma unroll
    for (int off = 1; off <= 8; off <<= 1) m = fmaxf(m, __shfl_xor(m, off));
    float sum = 0.f;
#pragma unroll
    for (int nt = 0; nt < 9; nt++) {
      float p = __expf(v[nt] - m);
      v[nt] = p;
      sum += p;
    }
#pragma unroll
    for (int off = 1; off <= 8; off <<= 1) sum += __shfl_xor(sum, off);
    float inv = 1.0f / sum;
    int prow = (quad * 4 + reg) * 200;
#pragma unroll
    for (int nt = 0; nt < 9; nt++)
      myP[prow + nt * 16 + l16] = f2bf(v[nt] * inv);
    myP[prow + 144 + l16] = 0;  // zero-pad tile 9 -> P width 160
  }
  __syncthreads();  // all waves done reading K from buf0

  // ---- scatter V^T into buf0 ([d][key], stride 208) -----------------------
#pragma unroll
  for (int i = 0; i < 7; i++) {
    int e = i * 256 + t;
    if (e < 1664) {
      int dg = e / 208;
      int slot = e - dg * 208;
#pragma unroll
      for (int j = 0; j < 8; j++) buf0[(dg * 8 + j) * 208 + slot] = vreg[i][j];
    }
  }
  __syncthreads();

  // ---- PV over the 160-key padded window ----------------------------------
  floatx4 oc[4] = {};
#pragma unroll
  for (int ks = 0; ks < 5; ks++) {
    bf16x8 ap = *(const bf16x8*)(myP + l16 * 200 + ks * 32 + quad * 8);
#pragma unroll
    for (int nt = 0; nt < 4; nt++) {
      bf16x8 bv =
          *(const bf16x8*)(buf0 + (nt * 16 + l16) * 208 + koff + ks * 32 + quad * 8);
      oc[nt] = MFMA16(ap, bv, oc[nt]);
    }
  }

  int srow = c * 64 + wave * 16 + quad * 4;
#pragma unroll
  for (int nt = 0; nt < 4; nt++) {
    u16* dp = ctx + (size_t)(b * S0 + srow) * HID + h * HD + nt * 16 + l16;
#pragma unroll
    for (int reg = 0; reg < 4; reg++)
      dp[(size_t)reg * HID] = f2bf(oc[nt][reg]);
  }
}

// ---------------------------------------------------------------------------
extern "C" void kernel_launch(void* const* d_in, const int* in_sizes, int n_in,
                              void* d_out, int out_size, void* d_ws, size_t ws_size,
                              hipStream_t stream) {
  const float* X = (const float*)d_in[0];
  const float* mask = (const float*)d_in[1];
  const float* Wq = (const float*)d_in[2];
  const float* bq = (const float*)d_in[3];
  const float* Wk = (const float*)d_in[4];
  const float* bk = (const float*)d_in[5];
  const float* Wv = (const float*)d_in[6];
  const float* bv = (const float*)d_in[7];
  const float* Wo = (const float*)d_in[8];
  const float* bo = (const float*)d_in[9];
  char* ws = (char*)d_ws;

  const size_t MB = 1048576;
  u16* cmask = (u16*)(ws + 256);               // 16 KB
  u16* cb = (u16*)(ws + 256 + 16384);          // 8 KB
  u16* cX = (u16*)(ws + 1 * MB);               // 16 MB (CTX aliases after gemm0)
  u16* WqkvT = (u16*)(ws + 17 * MB);           // 6 MB
  u16* WoT = (u16*)(ws + 23 * MB);             // 2 MB
  u16* QKV = (u16*)(ws + 25 * MB);             // 48 MB
  u16* CTX = cX;                               // alias: cX dead after gemm0

  const size_t per_qkv = (size_t)B_ * NH * S0 * HD;  // elements per Q/K/V

  prep<<<4096 + 48 + 1024, 256, 0, stream>>>(X, mask, Wq, bq, Wk, bk, Wv, bv,
                                             Wo, bo, cX, cmask, cb, WqkvT, WoT);
  gemm_bf16_tn<96, 0><<<dim3(64, 32), 256, 0, stream>>>(cX, WqkvT, cb, QKV, HID);
  attn_win<<<dim3(B_ * NH * 64), 256, 0, stream>>>(QKV, QKV + per_qkv,
                                                   QKV + 2 * per_qkv, cmask, CTX);
  gemm_bf16_tn<128, 1><<<dim3(64, 8), 256, 0, stream>>>(CTX, WoT, cb, d_out, HID);
}